// Round 1
// baseline (198.126 us; speedup 1.0000x reference)
//
#include <hip/hip_runtime.h>
#include <math.h>

// B=8, T=4096, H=8, D=64, fp32.
#define BB 8
#define TT 4096
#define HH 8
#define DD 64

typedef float f32x4_native __attribute__((ext_vector_type(4)));

__device__ __forceinline__ float sigmoidf_(float x) {
    return 1.0f / (1.0f + expf(-x));
}

// ---------------------------------------------------------------------------
// K1: per-(b,chunk) block of 128 threads (thread = (h,d4), float4 over D).
// Computes ONLY the chunk aggregate Z = zero-init scan over the chunk's L
// steps (no partial-out write: K3 recomputes from L3-hot inputs instead).
// Loads are batched 16-deep (v[8]+a[8]) so each thread keeps 16 dwordx4
// loads in flight -> latency-bound fix.
// ---------------------------------------------------------------------------
template<int NCv>
__global__ __launch_bounds__(128)
void k_agg(const float4* __restrict__ vals, const float4* __restrict__ aux,
           const float* __restrict__ w, float4* __restrict__ Z) {
    constexpr int L = TT / NCv;
    const int blk = blockIdx.x;
    const int b = blk / NCv, c = blk % NCv;   // NCv is pow2 -> shifts
    const int tid = threadIdx.x;
    const int h = tid >> 4;

    const float alpha = sigmoidf_(w[h]);
    const float onem  = 1.0f - alpha;
    const float fa    = (onem / fmaxf(onem, 1e-6f)) * alpha;

    // float4 index: ((b*T+t)*H + h)*D/4 + d4 = (b*T+t)*128 + tid
    int base = (b * TT + c * L) * 128 + tid;

    float4 y = make_float4(0.f, 0.f, 0.f, 0.f);
#pragma unroll
    for (int hh = 0; hh < L / 8; ++hh) {
        float4 v[8], a[8];
#pragma unroll
        for (int i = 0; i < 8; ++i) {
            v[i] = vals[base + (hh * 8 + i) * 128];
            a[i] = aux [base + (hh * 8 + i) * 128];
        }
#pragma unroll
        for (int i = 0; i < 8; ++i) {
            y.x = alpha * y.x + (onem * v[i].x + fa * a[i].x);
            y.y = alpha * y.y + (onem * v[i].y + fa * a[i].y);
            y.z = alpha * y.z + (onem * v[i].z + fa * a[i].z);
            y.w = alpha * y.w + (onem * v[i].w + fa * a[i].w);
        }
    }
    Z[(b * NCv + c) * 128 + tid] = y;
}

// ---------------------------------------------------------------------------
// K2: Kogge-Stone scan over the NCv chunk aggregates.
// Block = (b, h, d8): 8*8*8 = 512 blocks, NCv threads (thread = chunk c).
// Each thread owns one chunk row of 8 floats (2 float4 of its d-eighth).
// Combine: S[c] += aL^off * S[c-off].  P[c] = aL^c * v0 + S_inc[c-1]
// (= carry INTO chunk c; P[0] = v0).
// LDS row stride 9 floats (coprime with 32 banks -> conflict-free).
// ---------------------------------------------------------------------------
template<int NCv>
__global__ __launch_bounds__(512)
void k_scan(const float4* __restrict__ Z, const float* __restrict__ v0,
            const float* __restrict__ w, float4* __restrict__ P) {
    constexpr int L = TT / NCv;
    __shared__ float lds[NCv][9];

    const int blk = blockIdx.x;        // b*64 + h*8 + d8
    const int b  = blk >> 6;
    const int h  = (blk >> 3) & 7;
    const int d8 = blk & 7;
    const int r4 = h * 16 + d8 * 2;    // float4 offset within 128-f4 row
    const int tid = threadIdx.x;

    const float alpha = sigmoidf_(w[h]);
    const float aL = powf(alpha, (float)L);

    // Cooperative load: NCv rows * 2 float4 each, NCv threads -> 2 iters.
#pragma unroll
    for (int it = 0; it < 2; ++it) {
        int idx = it * NCv + tid;
        int c = idx >> 1, k = idx & 1;
        float4 z = Z[(b * NCv + c) * 128 + r4 + k];
        lds[c][k * 4 + 0] = z.x;
        lds[c][k * 4 + 1] = z.y;
        lds[c][k * 4 + 2] = z.z;
        lds[c][k * 4 + 3] = z.w;
    }
    __syncthreads();

    const int c = tid;    // thread c owns chunk c's 8-float row
    float s[8];
#pragma unroll
    for (int k = 0; k < 8; ++k) s[k] = lds[c][k];

    float m = aL;
    for (int off = 1; off < NCv; off <<= 1) {
        float tmp[8];
        const bool act = (c >= off);
        if (act) {
#pragma unroll
            for (int k = 0; k < 8; ++k) tmp[k] = lds[c - off][k];
        }
        __syncthreads();
        if (act) {
#pragma unroll
            for (int k = 0; k < 8; ++k) { s[k] += m * tmp[k]; lds[c][k] = s[k]; }
        }
        m *= m;
        __syncthreads();
    }

    // Carry into chunk c: P[c] = aL^c * v0 + S_inc[c-1]; P[0] = v0.
    const float pc = powf(alpha, (float)(L * c));
    const float4* v04 = (const float4*)v0;
#pragma unroll
    for (int k = 0; k < 2; ++k) {
        float4 vv = v04[r4 + k];
        float4 pr;
        if (c == 0) {
            pr = vv;
        } else {
            pr.x = pc * vv.x + lds[c - 1][k * 4 + 0];
            pr.y = pc * vv.y + lds[c - 1][k * 4 + 1];
            pr.z = pc * vv.z + lds[c - 1][k * 4 + 2];
            pr.w = pc * vv.w + lds[c - 1][k * 4 + 3];
        }
        P[(b * NCv + c) * 128 + r4 + k] = pr;
    }
}

// ---------------------------------------------------------------------------
// K3: recompute local scan from (L3-hot) inputs, fold in carry, write out
// ONCE with non-temporal stores (out is never re-read; nt keeps the inputs
// resident in L3 for the remaining reads of this pass).
//   out[t=c*L+i] = y_local[i] + alpha^(i+1) * P[c]
// ---------------------------------------------------------------------------
template<int NCv>
__global__ __launch_bounds__(128)
void k_out(const float4* __restrict__ vals, const float4* __restrict__ aux,
           const float* __restrict__ w, const float4* __restrict__ P,
           float4* __restrict__ out) {
    constexpr int L = TT / NCv;
    const int blk = blockIdx.x;
    const int b = blk / NCv, c = blk % NCv;
    const int tid = threadIdx.x;
    const int h = tid >> 4;

    const float alpha = sigmoidf_(w[h]);
    const float onem  = 1.0f - alpha;
    const float fa    = (onem / fmaxf(onem, 1e-6f)) * alpha;

    const float4 p = P[(b * NCv + c) * 128 + tid];
    int base = (b * TT + c * L) * 128 + tid;

    float4 y = make_float4(0.f, 0.f, 0.f, 0.f);
    float coef = alpha;
#pragma unroll
    for (int hh = 0; hh < L / 8; ++hh) {
        float4 v[8], a[8];
#pragma unroll
        for (int i = 0; i < 8; ++i) {
            v[i] = vals[base + (hh * 8 + i) * 128];
            a[i] = aux [base + (hh * 8 + i) * 128];
        }
#pragma unroll
        for (int i = 0; i < 8; ++i) {
            y.x = alpha * y.x + (onem * v[i].x + fa * a[i].x);
            y.y = alpha * y.y + (onem * v[i].y + fa * a[i].y);
            y.z = alpha * y.z + (onem * v[i].z + fa * a[i].z);
            y.w = alpha * y.w + (onem * v[i].w + fa * a[i].w);
            float4 o;
            o.x = y.x + coef * p.x;
            o.y = y.y + coef * p.y;
            o.z = y.z + coef * p.z;
            o.w = y.w + coef * p.w;
            __builtin_nontemporal_store(*(const f32x4_native*)&o,
                                        (f32x4_native*)&out[base + (hh * 8 + i) * 128]);
            coef *= alpha;
        }
    }
}

// ---------------------------------------------------------------------------
extern "C" void kernel_launch(void* const* d_in, const int* in_sizes, int n_in,
                              void* d_out, int out_size, void* d_ws, size_t ws_size,
                              hipStream_t stream) {
    const float4* vals = (const float4*)d_in[0];   // values  [B,T,H,D]
    const float4* aux  = (const float4*)d_in[1];   // aux     [B,T,H,D]
    const float*  v0   = (const float*)d_in[2];    // v0      [H,D] = 512
    const float*  w    = (const float*)d_in[3];    // weight  [H] = 8

    float4* out = (float4*)d_out;

    // Workspace: Z then P, each B*NCv*128 float4.
    const size_t need512 = 2ull * BB * 512 * 128 * sizeof(float4);  // ~16.8 MB

    if (ws_size >= need512) {
        constexpr int NCv = 512;   // L=8: 4096 blocks -> 8192 waves (full occupancy)
        float4* Z = (float4*)d_ws;
        float4* P = Z + (size_t)BB * NCv * 128;
        k_agg <NCv><<<BB * NCv,   128, 0, stream>>>(vals, aux, w, Z);
        k_scan<NCv><<<BB * HH * 8, NCv, 0, stream>>>(Z, v0, w, P);
        k_out <NCv><<<BB * NCv,   128, 0, stream>>>(vals, aux, w, P, out);
    } else {
        constexpr int NCv = 256;   // fallback if workspace is small (~8.4 MB)
        float4* Z = (float4*)d_ws;
        float4* P = Z + (size_t)BB * NCv * 128;
        k_agg <NCv><<<BB * NCv,   128, 0, stream>>>(vals, aux, w, Z);
        k_scan<NCv><<<BB * HH * 8, NCv, 0, stream>>>(Z, v0, w, P);
        k_out <NCv><<<BB * NCv,   128, 0, stream>>>(vals, aux, w, P, out);
    }
}

// Round 2
// 198.106 us; speedup vs baseline: 1.0001x; 1.0001x over previous
//
#include <hip/hip_runtime.h>
#include <math.h>

// B=8, T=4096, H=8, D=64, fp32.
#define BB 8
#define TT 4096
#define HH 8
#define NCC 256            // chunks per batch row
#define LC 16              // T / NCC steps per chunk
#define GRID (BB * NCC)    // 2048 blocks

typedef float f32x4 __attribute__((ext_vector_type(4)));

__device__ __forceinline__ float sigmoidf_(float x) {
    return 1.0f / (1.0f + expf(-x));
}

// ---------------------------------------------------------------------------
// Grid-wide barrier (sense-reversal via generation counter).
// Safe because all GRID blocks are co-resident: __launch_bounds__(128,4)
// caps VGPR at 128 -> 16 waves/CU -> 8 blocks/CU -> 2048 blocks resident.
// __threadfence() before arrive = agent release (L2 writeback, cross-XCD);
// after release = agent acquire (L2 invalidate) so normal loads see peers.
// Leaves cnt=0 afterwards, so repeated graph replays are self-consistent
// (a 16-byte memset at launch establishes the first-ever state).
// ---------------------------------------------------------------------------
__device__ __forceinline__ void gbar(unsigned int* cnt, unsigned int* gen) {
    __threadfence();
    __syncthreads();
    if (threadIdx.x == 0) {
        unsigned int g = __hip_atomic_load(gen, __ATOMIC_RELAXED, __HIP_MEMORY_SCOPE_AGENT);
        unsigned int old = __hip_atomic_fetch_add(cnt, 1u, __ATOMIC_ACQ_REL, __HIP_MEMORY_SCOPE_AGENT);
        if (old == (unsigned int)(GRID - 1)) {
            __hip_atomic_store(cnt, 0u, __ATOMIC_RELAXED, __HIP_MEMORY_SCOPE_AGENT);
            __hip_atomic_store(gen, g + 1u, __ATOMIC_RELEASE, __HIP_MEMORY_SCOPE_AGENT);
        } else {
            while (__hip_atomic_load(gen, __ATOMIC_ACQUIRE, __HIP_MEMORY_SCOPE_AGENT) == g)
                __builtin_amdgcn_s_sleep(8);
        }
    }
    __syncthreads();
    __threadfence();
}

// ---------------------------------------------------------------------------
// Single-pass fused kernel: inputs read ONCE, out written ONCE.
// Block = (b, c); thread = (h, d4). Chunk prefixes y[16] live in registers
// across the grid barrier (64 VGPRs).
// ---------------------------------------------------------------------------
__global__ __launch_bounds__(128, 4)
void k_fused(const float4* __restrict__ vals, const float4* __restrict__ aux,
             const float* __restrict__ v0, const float* __restrict__ w,
             float4* __restrict__ Z, float4* __restrict__ P,
             unsigned int* __restrict__ bar, float4* __restrict__ out) {
    __shared__ float lds[128][9];   // pair-KS rows; stride 9 floats, conflict-free

    const int blk = blockIdx.x;
    const int b = blk >> 8;           // blk / NCC
    const int c = blk & (NCC - 1);
    const int tid = threadIdx.x;
    const int h = tid >> 4;

    const float alpha = sigmoidf_(w[h]);
    const float onem  = 1.0f - alpha;
    const float fa    = (onem / fmaxf(onem, 1e-6f)) * alpha;

    // float4 index: ((b*T+t)*H + h)*D/4 + d4 = (b*T+t)*128 + tid
    const int base = (b * TT + c * LC) * 128 + tid;

    // ---- phase 1: local zero-init scan; keep all L prefixes in registers ----
    float4 y[LC];
    {
        float4 yy = make_float4(0.f, 0.f, 0.f, 0.f);
#pragma unroll
        for (int i = 0; i < LC; ++i) {
            float4 v = vals[base + i * 128];
            float4 a = aux[base + i * 128];
            yy.x = alpha * yy.x + onem * v.x + fa * a.x;
            yy.y = alpha * yy.y + onem * v.y + fa * a.y;
            yy.z = alpha * yy.z + onem * v.z + fa * a.z;
            yy.w = alpha * yy.w + onem * v.w + fa * a.w;
            y[i] = yy;
        }
        Z[(b * NCC + c) * 128 + tid] = yy;   // chunk aggregate
    }

    gbar(bar, bar + 1);

    // ---- phase 2: scan chunk aggregates (blocks 0..511 only) ----
    // scan block = (sb, sh, d8): 8*8*8 = 512; thread t = pair of chunks (2t,2t+1)
    if (blk < BB * HH * 8) {
        const int sb = blk >> 6;
        const int sh = (blk >> 3) & 7;
        const int d8 = blk & 7;
        const int r4 = sh * 16 + d8 * 2;     // float4 offset of 8-float slice
        const float sa  = sigmoidf_(w[sh]);
        const float aL  = powf(sa, (float)LC);
        const float aL2 = aL * aL;
        const int t = tid;                   // pair index 0..127

        float z0[8], s[8];
        {
            float4 za = Z[(sb * NCC + 2 * t) * 128 + r4];
            float4 zb = Z[(sb * NCC + 2 * t) * 128 + r4 + 1];
            float4 zc = Z[(sb * NCC + 2 * t + 1) * 128 + r4];
            float4 zd = Z[(sb * NCC + 2 * t + 1) * 128 + r4 + 1];
            z0[0]=za.x; z0[1]=za.y; z0[2]=za.z; z0[3]=za.w;
            z0[4]=zb.x; z0[5]=zb.y; z0[6]=zb.z; z0[7]=zb.w;
            float z1[8] = {zc.x,zc.y,zc.z,zc.w,zd.x,zd.y,zd.z,zd.w};
#pragma unroll
            for (int k = 0; k < 8; ++k) { s[k] = z1[k] + aL * z0[k]; lds[t][k] = s[k]; }
        }
        __syncthreads();

        // Kogge-Stone over 128 pairs, decay aL^2 per pair
        float m = aL2;
        for (int off = 1; off < 128; off <<= 1) {
            float tmp[8];
            const bool act = (t >= off);
            if (act) {
#pragma unroll
                for (int k = 0; k < 8; ++k) tmp[k] = lds[t - off][k];
            }
            __syncthreads();
            if (act) {
#pragma unroll
                for (int k = 0; k < 8; ++k) { s[k] += m * tmp[k]; lds[t][k] = s[k]; }
            }
            m *= m;
            __syncthreads();
        }
        // lds[t] = S~[t] = inclusive scan value at chunk 2t+1

        float stm1[8];
#pragma unroll
        for (int k = 0; k < 8; ++k) stm1[k] = (t > 0) ? lds[t - 1][k] : 0.f;

        // P[c] = alpha^(L*c) * v0 + S[c-1];  P[0] = v0.
        const float pc0 = powf(sa, (float)(LC * 2 * t));
        const float pc1 = pc0 * aL;
        const float* v0p = v0 + sh * 64 + d8 * 8;
        float4* Pp = P + (sb * NCC + 2 * t) * 128 + r4;
        float p0[8], p1[8];
#pragma unroll
        for (int k = 0; k < 8; ++k) {
            float vv  = v0p[k];
            float s2t = z0[k] + aL * stm1[k];   // S[2t]
            p0[k] = pc0 * vv + stm1[k];         // carry into chunk 2t
            p1[k] = pc1 * vv + s2t;             // carry into chunk 2t+1
        }
        float4 q;
        q.x=p0[0]; q.y=p0[1]; q.z=p0[2]; q.w=p0[3]; Pp[0]   = q;
        q.x=p0[4]; q.y=p0[5]; q.z=p0[6]; q.w=p0[7]; Pp[1]   = q;
        q.x=p1[0]; q.y=p1[1]; q.z=p1[2]; q.w=p1[3]; Pp[128] = q;
        q.x=p1[4]; q.y=p1[5]; q.z=p1[6]; q.w=p1[7]; Pp[129] = q;
    }

    gbar(bar, bar + 1);

    // ---- phase 3: apply carry from registers, single nt write of out ----
    const float4 p = P[(b * NCC + c) * 128 + tid];
    float coef = alpha;
#pragma unroll
    for (int i = 0; i < LC; ++i) {
        float4 o;
        o.x = y[i].x + coef * p.x;
        o.y = y[i].y + coef * p.y;
        o.z = y[i].z + coef * p.z;
        o.w = y[i].w + coef * p.w;
        __builtin_nontemporal_store(*(const f32x4*)&o, (f32x4*)&out[base + i * 128]);
        coef *= alpha;
    }
}

// ===========================================================================
// Fallback 3-kernel path (proven-correct R1 pipeline, NC=256) — used only if
// the occupancy query ever reports < 8 blocks/CU for k_fused.
// ===========================================================================
__global__ __launch_bounds__(128)
void k_agg(const float4* __restrict__ vals, const float4* __restrict__ aux,
           const float* __restrict__ w, float4* __restrict__ Z) {
    const int blk = blockIdx.x;
    const int b = blk >> 8, c = blk & (NCC - 1);
    const int tid = threadIdx.x;
    const int h = tid >> 4;
    const float alpha = sigmoidf_(w[h]);
    const float onem  = 1.0f - alpha;
    const float fa    = (onem / fmaxf(onem, 1e-6f)) * alpha;
    const int base = (b * TT + c * LC) * 128 + tid;
    float4 yy = make_float4(0.f, 0.f, 0.f, 0.f);
#pragma unroll
    for (int i = 0; i < LC; ++i) {
        float4 v = vals[base + i * 128];
        float4 a = aux[base + i * 128];
        yy.x = alpha * yy.x + onem * v.x + fa * a.x;
        yy.y = alpha * yy.y + onem * v.y + fa * a.y;
        yy.z = alpha * yy.z + onem * v.z + fa * a.z;
        yy.w = alpha * yy.w + onem * v.w + fa * a.w;
    }
    Z[(b * NCC + c) * 128 + tid] = yy;
}

__global__ __launch_bounds__(256)
void k_scan(const float4* __restrict__ Z, const float* __restrict__ v0,
            const float* __restrict__ w, float4* __restrict__ P) {
    __shared__ float lds[NCC][9];
    const int blk = blockIdx.x;        // b*64 + h*8 + d8
    const int b  = blk >> 6;
    const int h  = (blk >> 3) & 7;
    const int d8 = blk & 7;
    const int r4 = h * 16 + d8 * 2;
    const int tid = threadIdx.x;
    const float alpha = sigmoidf_(w[h]);
    const float aL = powf(alpha, (float)LC);
#pragma unroll
    for (int it = 0; it < 2; ++it) {
        int idx = it * NCC + tid;
        int cc = idx >> 1, k = idx & 1;
        float4 z = Z[(b * NCC + cc) * 128 + r4 + k];
        lds[cc][k * 4 + 0] = z.x; lds[cc][k * 4 + 1] = z.y;
        lds[cc][k * 4 + 2] = z.z; lds[cc][k * 4 + 3] = z.w;
    }
    __syncthreads();
    const int c = tid;
    float s[8];
#pragma unroll
    for (int k = 0; k < 8; ++k) s[k] = lds[c][k];
    float m = aL;
    for (int off = 1; off < NCC; off <<= 1) {
        float tmp[8];
        const bool act = (c >= off);
        if (act) {
#pragma unroll
            for (int k = 0; k < 8; ++k) tmp[k] = lds[c - off][k];
        }
        __syncthreads();
        if (act) {
#pragma unroll
            for (int k = 0; k < 8; ++k) { s[k] += m * tmp[k]; lds[c][k] = s[k]; }
        }
        m *= m;
        __syncthreads();
    }
    const float pc = powf(alpha, (float)(LC * c));
    const float4* v04 = (const float4*)v0;
#pragma unroll
    for (int k = 0; k < 2; ++k) {
        float4 vv = v04[r4 + k];
        float4 pr;
        if (c == 0) {
            pr = vv;
        } else {
            pr.x = pc * vv.x + lds[c - 1][k * 4 + 0];
            pr.y = pc * vv.y + lds[c - 1][k * 4 + 1];
            pr.z = pc * vv.z + lds[c - 1][k * 4 + 2];
            pr.w = pc * vv.w + lds[c - 1][k * 4 + 3];
        }
        P[(b * NCC + c) * 128 + r4 + k] = pr;
    }
}

__global__ __launch_bounds__(128)
void k_out(const float4* __restrict__ vals, const float4* __restrict__ aux,
           const float* __restrict__ w, const float4* __restrict__ P,
           float4* __restrict__ out) {
    const int blk = blockIdx.x;
    const int b = blk >> 8, c = blk & (NCC - 1);
    const int tid = threadIdx.x;
    const int h = tid >> 4;
    const float alpha = sigmoidf_(w[h]);
    const float onem  = 1.0f - alpha;
    const float fa    = (onem / fmaxf(onem, 1e-6f)) * alpha;
    const float4 p = P[(b * NCC + c) * 128 + tid];
    const int base = (b * TT + c * LC) * 128 + tid;
    float4 yy = make_float4(0.f, 0.f, 0.f, 0.f);
    float coef = alpha;
#pragma unroll
    for (int i = 0; i < LC; ++i) {
        float4 v = vals[base + i * 128];
        float4 a = aux[base + i * 128];
        yy.x = alpha * yy.x + onem * v.x + fa * a.x;
        yy.y = alpha * yy.y + onem * v.y + fa * a.y;
        yy.z = alpha * yy.z + onem * v.z + fa * a.z;
        yy.w = alpha * yy.w + onem * v.w + fa * a.w;
        float4 o;
        o.x = yy.x + coef * p.x;
        o.y = yy.y + coef * p.y;
        o.z = yy.z + coef * p.z;
        o.w = yy.w + coef * p.w;
        __builtin_nontemporal_store(*(const f32x4*)&o, (f32x4*)&out[base + i * 128]);
        coef *= alpha;
    }
}

// ---------------------------------------------------------------------------
extern "C" void kernel_launch(void* const* d_in, const int* in_sizes, int n_in,
                              void* d_out, int out_size, void* d_ws, size_t ws_size,
                              hipStream_t stream) {
    const float4* vals = (const float4*)d_in[0];   // values  [B,T,H,D]
    const float4* aux  = (const float4*)d_in[1];   // aux     [B,T,H,D]
    const float*  v0   = (const float*)d_in[2];    // v0      [H,D] = 512
    const float*  w    = (const float*)d_in[3];    // weight  [H] = 8
    float4* out = (float4*)d_out;

    // Workspace: Z (4 MB), P (4 MB), barrier counters (16 B).
    float4* Z = (float4*)d_ws;
    float4* P = Z + (size_t)BB * NCC * 128;
    unsigned int* bar = (unsigned int*)((char*)d_ws + 2ull * BB * NCC * 128 * sizeof(float4));

    // Verify guaranteed co-residency of all GRID blocks (host-side calc,
    // capture-safe). Falls back to the 3-kernel pipeline if it ever fails.
    int nb = 0;
    hipError_t e = hipOccupancyMaxActiveBlocksPerMultiprocessor(&nb, k_fused, 128, 0);
    bool coop_ok = (e == hipSuccess) && ((long)nb * 256 >= GRID);

    if (coop_ok) {
        hipMemsetAsync(bar, 0, 16, stream);   // barrier state for this replay
        k_fused<<<GRID, 128, 0, stream>>>(vals, aux, v0, w, Z, P, bar, out);
    } else {
        k_agg <<<GRID, 128, 0, stream>>>(vals, aux, w, Z);
        k_scan<<<BB * HH * 8, NCC, 0, stream>>>(Z, v0, w, P);
        k_out <<<GRID, 128, 0, stream>>>(vals, aux, w, P, out);
    }
}